// Round 8
// baseline (221.740 us; speedup 1.0000x reference)
//
#include <hip/hip_runtime.h>
#include <hip/hip_fp16.h>

#define IN_F   100000
#define OUT_F  100000
#define NNZ_N  1600000
#define TC     256
#define TBLK   ((IN_F + TC - 1) / TC)      // 391 transpose blocks
#define SBLK   ((NNZ_N + 255) / 256)       // 6250 scan blocks
#define RBLK   ((OUT_F + 63) / 64)         // 1563 spmm blocks
#define ED_CAP 2048                         // staged edges/block (mean 1024, sigma 32)

__device__ __forceinline__ float2 h2f(unsigned u) {
    const __half2 h = *reinterpret_cast<const __half2*>(&u);
    return __half22float2(h);
}

// ---------------------------------------------------------------------------
// Prep (fused, proven round-6): blocks [0,TBLK) transpose x (64,IN) f32 ->
// xh (IN,64) f16 (u32 word: col*32 + p, pair p = batches 2p,2p+1). Blocks
// [TBLK,..) do the rowstart linear scan over sorted rows.
// ---------------------------------------------------------------------------
__global__ __launch_bounds__(256) void k_prep(
    const float* __restrict__ x,
    const int*   __restrict__ rows,
    unsigned* __restrict__ xh,
    int*      __restrict__ rstart) {
    __shared__ unsigned tile[TC][33];
    const int bid = blockIdx.x;
    const int t   = threadIdx.x;

    if (bid < TBLK) {
        const int i0   = bid * TC;
        const int colr = i0 + t;
        if (colr < IN_F) {
            #pragma unroll 8
            for (int p = 0; p < 32; ++p) {
                const float a = x[(size_t)(2 * p)     * IN_F + colr];
                const float b = x[(size_t)(2 * p + 1) * IN_F + colr];
                const __half2 h = __floats2half2_rn(a, b);
                tile[t][p] = *reinterpret_cast<const unsigned*>(&h);
            }
        }
        __syncthreads();
        const int u  = t & 31;              // batch pair
        const int c8 = t >> 5;
        for (int cc = c8; cc < TC; cc += 8) {
            const int col = i0 + cc;
            if (col < IN_F)
                xh[(size_t)col * 32 + u] = tile[cc][u];
        }
    } else {
        const int e = (bid - TBLK) * 256 + t;
        if (e >= NNZ_N) return;
        const int cur  = rows[e];
        const int prev = (e == 0) ? -1 : rows[e - 1];
        for (int r = prev + 1; r <= cur; ++r) rstart[r] = e;
        if (e == NNZ_N - 1)
            for (int r = cur + 1; r <= OUT_F; ++r) rstart[r] = NNZ_N;
    }
}

// edge meta load (LDS uint2, one ds_read_b64/edge) with tail masking
#define LOADM(C, V, B) do {                                                    \
    _Pragma("unroll")                                                          \
    for (int j_ = 0; j_ < 8; ++j_) {                                           \
        const int i_ = ((B) + j_ < n) ? (B) + j_ : n - 1;                      \
        const uint2 e_ = euv[i_];                                              \
        (C)[j_] = (int)e_.x;                                                   \
        (V)[j_] = ((B) + j_ < n) ? __uint_as_float(e_.y) : 0.f;                \
    } } while (0)

#define GATH(U, C) do {                                                        \
    _Pragma("unroll")                                                          \
    for (int j_ = 0; j_ < 8; ++j_)                                             \
        (U)[j_] = xh4[(size_t)(C)[j_] * 8 + sub];                              \
    } while (0)

#define FMA8(U, V) do {                                                        \
    _Pragma("unroll")                                                          \
    for (int j_ = 0; j_ < 8; ++j_) {                                           \
        float2 f_;                                                             \
        f_ = h2f((U)[j_].x); acc[0] = fmaf((V)[j_], f_.x, acc[0]); acc[1] = fmaf((V)[j_], f_.y, acc[1]); \
        f_ = h2f((U)[j_].y); acc[2] = fmaf((V)[j_], f_.x, acc[2]); acc[3] = fmaf((V)[j_], f_.y, acc[3]); \
        f_ = h2f((U)[j_].z); acc[4] = fmaf((V)[j_], f_.x, acc[4]); acc[5] = fmaf((V)[j_], f_.y, acc[5]); \
        f_ = h2f((U)[j_].w); acc[6] = fmaf((V)[j_], f_.x, acc[6]); acc[7] = fmaf((V)[j_], f_.y, acc[7]); \
    } } while (0)

// ---------------------------------------------------------------------------
// SpMM: block = 512 threads = 8 waves = 64 rows; 8-lane group owns one row,
// lane sub in [0,8) covers batches 8sub..8sub+7 (uint4 = 8 halves = one
// 128B line per edge per group). Edge list staged coalesced into LDS as
// packed uint2 (ds_read_b64 broadcasts in the loop). Inner loop is a 2-stage
// ping-pong software pipeline: meta+gathers for iteration i+1 issue BEFORE
// iteration i's FMAs -> sustained ~10-14 gather lines in flight per lane
// (vs ~4-5 with the plain unroll-8). fp32 register accumulate; direct tile
// write (no atomics); coalesced transpose epilogue.
// ---------------------------------------------------------------------------
__global__ __launch_bounds__(512, 4) void k_spmm(
    const uint4* __restrict__ xh4,        // col*8 + sub
    const int*   __restrict__ rstart,
    const int*   __restrict__ cols,
    const float* __restrict__ vals,
    const float* __restrict__ bias,
    float* __restrict__ out) {
    __shared__ int   rs[65];
    __shared__ uint2 euv[ED_CAP];
    __shared__ float tile[64][65];
    const int r0   = blockIdx.x * 64;
    const int t    = threadIdx.x;
    const int lane = t & 63;
    const int w    = t >> 6;

    if (t < 65) {
        int idx = r0 + t; if (idx > OUT_F) idx = OUT_F;
        rs[t] = rstart[idx];
    }
    __syncthreads();

    const int s  = rs[0];
    const int ne = rs[64] - s;
    const int ns = (ne < ED_CAP) ? ne : ED_CAP;
    for (int i = t; i < ns; i += 512)
        euv[i] = make_uint2((unsigned)cols[s + i], __float_as_uint(vals[s + i]));
    __syncthreads();

    const int gg  = t >> 3;               // group -> local row 0..63
    const int sub = t & 7;                // batch octet
    const int ls  = rs[gg]     - s;       // local [ls, n) edge range
    const int n   = rs[gg + 1] - s;

    float acc[8];
    #pragma unroll
    for (int i = 0; i < 8; ++i) acc[i] = 0.f;

    if (ne <= ED_CAP) {
        if (ls < n) {
            int cA[8]; float vA[8]; uint4 uA[8];
            int cB[8]; float vB[8]; uint4 uB[8];
            LOADM(cA, vA, ls);
            GATH(uA, cA);
            for (int base = ls; base < n; base += 16) {
                const int nb = base + 8;
                if (nb < n) { LOADM(cB, vB, nb); GATH(uB, cB); }
                FMA8(uA, vA);
                const int nn = base + 16;
                if (nn < n) { LOADM(cA, vA, nn); GATH(uA, cA); }
                if (nb < n) FMA8(uB, vB);
            }
        }
    } else {                               // ~32-sigma event; correctness only
        for (int base = ls; base < n; base += 8) {
            int c[8]; float v[8];
            #pragma unroll
            for (int j = 0; j < 8; ++j) {
                const int i = (base + j < n) ? base + j : n - 1;
                c[j] = cols[s + i];
                v[j] = (base + j < n) ? vals[s + i] : 0.f;
            }
            uint4 u[8];
            #pragma unroll
            for (int j = 0; j < 8; ++j)
                u[j] = xh4[(size_t)c[j] * 8 + sub];
            #pragma unroll
            for (int j = 0; j < 8; ++j) {
                float2 f_;
                f_ = h2f(u[j].x); acc[0] = fmaf(v[j], f_.x, acc[0]); acc[1] = fmaf(v[j], f_.y, acc[1]);
                f_ = h2f(u[j].y); acc[2] = fmaf(v[j], f_.x, acc[2]); acc[3] = fmaf(v[j], f_.y, acc[3]);
                f_ = h2f(u[j].z); acc[4] = fmaf(v[j], f_.x, acc[4]); acc[5] = fmaf(v[j], f_.y, acc[5]);
                f_ = h2f(u[j].w); acc[6] = fmaf(v[j], f_.x, acc[6]); acc[7] = fmaf(v[j], f_.y, acc[7]);
            }
        }
    }

    // tile[gg][8sub+i]: bank = (gg + 8sub + i) mod 32 -> 2 lanes/bank = free
    #pragma unroll
    for (int i = 0; i < 8; ++i) tile[gg][(sub << 3) + i] = acc[i];
    __syncthreads();

    const int rc = r0 + lane;
    if (rc < OUT_F) {
        const float bv = bias[rc];
        for (int bb = w; bb < 64; bb += 8)
            out[(size_t)bb * OUT_F + rc] = tile[lane][bb] + bv;
    }
}

// ---------------------------------------------------------------------------
// Fallback (insufficient ws): gather from native x layout. Correct, slow.
// ---------------------------------------------------------------------------
__global__ __launch_bounds__(256) void k_spmm_fallback(
    const float* __restrict__ x,
    const float* __restrict__ vals,
    const int*   __restrict__ rows,
    const int*   __restrict__ cols,
    const float* __restrict__ bias,
    float* __restrict__ out) {
    __shared__ int   rstart[65];
    __shared__ float tile[64][65];
    const int r0   = blockIdx.x * 64;
    const int t    = threadIdx.x;
    const int lane = t & 63;
    const int w    = t >> 6;
    if (t < 65) {
        const int target = r0 + t;
        int lo = 0, hi = NNZ_N;
        while (lo < hi) {
            const int mid = (lo + hi) >> 1;
            if (rows[mid] < target) lo = mid + 1; else hi = mid;
        }
        rstart[t] = lo;
    }
    __syncthreads();
    for (int j = w; j < 64; j += 4) {
        const int s = rstart[j], e = rstart[j + 1];
        float acc = 0.f;
        const size_t base = (size_t)lane * IN_F;
        for (int idx = s; idx < e; ++idx)
            acc = fmaf(vals[idx], x[base + cols[idx]], acc);
        tile[j][lane] = acc;
    }
    __syncthreads();
    const int c = lane;
    if (r0 + c < OUT_F) {
        const float bv = bias[r0 + c];
        for (int bb = w; bb < 64; bb += 4)
            out[(size_t)bb * OUT_F + (r0 + c)] = tile[c][bb] + bv;
    }
}

extern "C" void kernel_launch(void* const* d_in, const int* in_sizes, int n_in,
                              void* d_out, int out_size, void* d_ws, size_t ws_size,
                              hipStream_t stream) {
    const float* x      = (const float*)d_in[0];
    const float* values = (const float*)d_in[1];
    const float* bias   = (const float*)d_in[2];
    const int*   rows   = (const int*)d_in[3];
    const int*   cols   = (const int*)d_in[4];
    float*       out    = (float*)d_out;

    const size_t xh_bytes = (size_t)IN_F * 32 * sizeof(unsigned);   // 12.8 MB
    const size_t rs_off   = (xh_bytes + 255) & ~(size_t)255;
    const size_t need     = rs_off + (size_t)(OUT_F + 1) * sizeof(int); // ~13.2 MB

    if (ws_size >= need) {
        unsigned* xh     = (unsigned*)d_ws;
        int*      rstart = (int*)((char*)d_ws + rs_off);
        k_prep<<<TBLK + SBLK, 256, 0, stream>>>(x, rows, xh, rstart);
        k_spmm<<<RBLK, 512, 0, stream>>>((const uint4*)xh, rstart, cols, values, bias, out);
    } else {
        k_spmm_fallback<<<RBLK, 256, 0, stream>>>(x, values, rows, cols, bias, out);
    }
}